// Round 14
// baseline (1516.375 us; speedup 1.0000x reference)
//
#include <hip/hip_runtime.h>
#include <hip/hip_bf16.h>
#include <cstdint>
#include <cstddef>

#define NN 30000
#define EE 150000
#define BASE_XS 120 // k_base x-blocks per chunk-p (>= ceil(30000/256)=118, mult of 8)
#define LIN_XS 120  // k_lin2 x-blocks per p (>= ceil(30000/256)=118, mult of 8)

using u16 = unsigned short;
using u32 = unsigned int;

__device__ __forceinline__ float bl2f(u16 u) { return __uint_as_float(((u32)u) << 16); }
__device__ __forceinline__ u16 f2bl(float f) {
    u32 x = __float_as_uint(f);
    return (u16)((x + 0x7fffu + ((x >> 16) & 1u)) >> 16);
}
__device__ __forceinline__ u32 pack2(float a, float b) {
    return (u32)f2bl(a) | ((u32)f2bl(b) << 16);
}

// ---------------- CSR build ----------------
__global__ void k_count(const int* __restrict__ dst, int* __restrict__ cnt) {
    int e = blockIdx.x * 256 + threadIdx.x;
    if (e < EE) atomicAdd(&cnt[dst[e]], 1);
}

__global__ void k_scan(const int* __restrict__ cnt, int* __restrict__ offs) {
    __shared__ int ss[1024];
    int t = threadIdx.x;
    int base = t * 30;
    int s = 0;
    for (int i = 0; i < 30; i++) { int idx = base + i; if (idx < NN) s += cnt[idx]; }
    ss[t] = s; __syncthreads();
    for (int off = 1; off < 1024; off <<= 1) {
        int v = (t >= off) ? ss[t - off] : 0;
        __syncthreads();
        ss[t] += v;
        __syncthreads();
    }
    int run = (t == 0) ? 0 : ss[t - 1];
    for (int i = 0; i < 30; i++) {
        int idx = base + i;
        if (idx < NN) { offs[idx] = run; run += cnt[idx]; }
    }
    if (t == 1023) offs[NN] = run;
}

__global__ void k_scatter(const int* __restrict__ src, const int* __restrict__ dst,
                          const int* __restrict__ offs, int* __restrict__ fill,
                          int* __restrict__ csr) {
    int e = blockIdx.x * 256 + threadIdx.x;
    if (e < EE) {
        int d = dst[e];
        int p = offs[d] + atomicAdd(&fill[d], 1);
        csr[p] = src[e];
    }
}

// ---------------- k_wqt: transpose agg-part of W_post into c-major layout --------
__global__ void k_wqt(const float* __restrict__ W_post, float* __restrict__ wqt) {
    int idx = blockIdx.x * 256 + threadIdx.x;
    if (idx >= 270000) return;
    int j = idx % 15;
    int grp = (idx / 15) % 3;
    int s4 = (idx / 45) % 4;
    int c = (idx / 180) % 75;
    int lt = idx / 13500;
    wqt[idx] = W_post[(size_t)lt * 975 * 15 + (size_t)(75 + grp * 300 + s4 * 75 + c) * 15 + j];
}

// ---------------- k_badj: bladj[l][c] = bl[c] + sum_k bq[k]*Wl[k][c]  (exact fold) ----
__global__ void k_badj(const float* __restrict__ b_lin, const float* __restrict__ b_post,
                       const float* __restrict__ W_lin, float* __restrict__ bladj) {
    int idx = blockIdx.x * 256 + threadIdx.x;
    if (idx >= 300) return;
    int l = idx / 75, c = idx % 75;
    float a = b_lin[l * 75 + c];
    const float* bq = b_post + l * 75;
    const float* Wl = W_lin + (size_t)l * 75 * 75;
    for (int k = 0; k < 75; k++) a = fmaf(bq[k], Wl[k * 75 + c], a);
    bladj[idx] = a;
}

// ---------------- k_wm: fold x-part through W_lin ----------------
__global__ void k_wm(const float* __restrict__ W_post, const float* __restrict__ W_lin,
                     float* __restrict__ Mf) {
    int idx = blockIdx.x * 256 + threadIdx.x;
    if (idx >= 22500) return;
    int l = idx / 5625;
    int c = (idx / 75) % 75;
    int o = idx % 75;
    const float* Wq = W_post + (size_t)l * 5 * 975 * 15;
    const float* Wl = W_lin + (size_t)l * 75 * 75;
    float a = 0.f;
    for (int t5 = 0; t5 < 5; t5++) {
        const float* wr = Wq + (size_t)t5 * 975 * 15 + (size_t)c * 15;
        const float* lr = Wl + (size_t)(t5 * 15) * 75 + o;
#pragma unroll
        for (int j = 0; j < 15; j++) a = fmaf(wr[j], lr[(size_t)j * 75], a);
    }
    Mf[idx] = a;
}

// ---------------- pre linear: hT[75][NN] f32 (col-major) + hB[n][40] bf16 pairs ------
__global__ void k_pre(const float* __restrict__ x, const float* __restrict__ pw,
                      const float* __restrict__ pb, float* __restrict__ hT,
                      u32* __restrict__ hB) {
    int n = blockIdx.x * 256 + threadIdx.x;
    if (n >= NN) return;
    float x0 = x[2 * n], x1 = x[2 * n + 1];
    float buf[80];
#pragma unroll
    for (int c = 0; c < 80; c++)
        buf[c] = (c < 75) ? fmaf(x0, pw[c], fmaf(x1, pw[75 + c], pb[c])) : 0.f;
#pragma unroll
    for (int c = 0; c < 75; c++)
        hT[(size_t)c * NN + n] = buf[c];
    uint4* bp4 = (uint4*)(hB + (size_t)n * 40);
#pragma unroll
    for (int w = 0; w < 10; w++)
        bp4[w] = make_uint4(pack2(buf[8 * w], buf[8 * w + 1]), pack2(buf[8 * w + 2], buf[8 * w + 3]),
                            pack2(buf[8 * w + 4], buf[8 * w + 5]), pack2(buf[8 * w + 6], buf[8 * w + 7]));
}

// ---- unpack helper: float k (0..7) from uint4 of bf16 pairs ----
__device__ __forceinline__ float upk(const uint4& a, int k) {
    u32 u = (k < 2) ? a.x : (k < 4) ? a.y : (k < 6) ? a.z : a.w;
    return __uint_as_float((k & 1) ? (u & 0xffff0000u) : (u << 16));
}

// ---- single-row inner: 1 row x 30 outputs, uniform weights (wA,wB 15-col slices) ----
__device__ __forceinline__ void gemm30s(const uint4* __restrict__ h,
                                        const float* __restrict__ wA,
                                        const float* __restrict__ wB,
                                        float acc[30]) {
    for (int fq = 0; fq < 9; fq++) {
        uint4 a0 = h[fq];
#pragma unroll
        for (int k = 0; k < 8; k++) {
            float i0 = upk(a0, k);
            const float* ra = wA + (fq * 8 + k) * 75;
            const float* rb = wB + (fq * 8 + k) * 75;
#pragma unroll
            for (int j = 0; j < 15; j++) acc[j] = fmaf(i0, ra[j], acc[j]);
#pragma unroll
            for (int j = 0; j < 15; j++) acc[15 + j] = fmaf(i0, rb[j], acc[15 + j]);
        }
    }
    uint4 a0 = h[9];
#pragma unroll
    for (int k = 0; k < 3; k++) {
        float i0 = upk(a0, k);
        const float* ra = wA + (72 + k) * 75;
        const float* rb = wB + (72 + k) * 75;
#pragma unroll
        for (int j = 0; j < 15; j++) acc[j] = fmaf(i0, ra[j], acc[j]);
#pragma unroll
        for (int j = 0; j < 15; j++) acc[15 + j] = fmaf(i0, rb[j], acc[15 + j]);
    }
}

// chunk p (0..12) -> weight slice pointers (15-col groups A and B)
__device__ __forceinline__ void chunk_w(int p, const float* Wp, int half_off,
                                        const float** wA, const float** wB, bool* full) {
    int cg = p * 2;
    int tA = cg / 5, cA = (cg % 5) * 15;
    *full = p < 12;
    int cg1 = *full ? cg + 1 : cg;
    int tB = cg1 / 5, cB = (cg1 % 5) * 15;
    *wA = Wp + ((size_t)tA * 150 + half_off) * 75 + cA;
    *wB = Wp + ((size_t)tB * 150 + half_off) * 75 + cB;
}

// ---- pack 30 accs into a 15-u32 (or 8 for tail chunk) row slice ----
__device__ __forceinline__ void pack_row(u32* rp, const float* a, bool full) {
    if (full) {
#pragma unroll
        for (int w = 0; w < 15; w++) rp[w] = pack2(a[2 * w], a[2 * w + 1]);
    } else {
#pragma unroll
        for (int w = 0; w < 7; w++) rp[w] = pack2(a[2 * w], a[2 * w + 1]);
        rp[7] = pack2(a[14], 0.f);
    }
}

// ---------------- k_base: 1 node/thread x 13 chunks, BOTH halves, chunk-major out ----
// baseb32/srcb32 layout: [13][NN][15] u32 -> each thread writes 15 u32 fully
// contiguous per half (r3-proven coalesced-write fix); wave writes 3.8 KB linear.
// No partial-line RMW -> co-residency constraint gone -> 1560 blocks (~6 waves/SIMD).
__global__ __launch_bounds__(256) void k_base(const u32* __restrict__ hB,
                                              const float* __restrict__ Wp,
                                              const float* __restrict__ bp,
                                              u32* __restrict__ baseb32,
                                              u32* __restrict__ srcb32) {
    int b = blockIdx.x;
    int p = b / BASE_XS;
    int xx = b - p * BASE_XS;
    int n = xx * 256 + threadIdx.x;
    if (n >= NN) return;
    uint4 h[10];
    const uint4* hp = (const uint4*)(hB + (size_t)n * 40);
#pragma unroll
    for (int w = 0; w < 10; w++) h[w] = hp[w];
    int o0 = p * 30;
    size_t slot = ((size_t)p * NN + n) * 15;
    {   // dst half (with bias)
        const float *wA, *wB; bool full;
        chunk_w(p, Wp, 0, &wA, &wB, &full);
        float acc[30];
#pragma unroll
        for (int j = 0; j < 15; j++) acc[j] = bp[o0 + j];
#pragma unroll
        for (int j = 0; j < 15; j++) acc[15 + j] = full ? bp[o0 + 15 + j] : 0.f;
        gemm30s(h, wA, wB, acc);
        pack_row(baseb32 + slot, acc, full);
    }
    {   // src half (no bias)
        const float *wA, *wB; bool full;
        chunk_w(p, Wp, 75, &wA, &wB, &full);
        float acc[30];
#pragma unroll
        for (int j = 0; j < 30; j++) acc[j] = 0.f;
        gemm30s(h, wA, wB, acc);
        pack_row(srcb32 + slot, acc, full);
    }
}

// ---------------- k_agg: per-node stats via chunk-major srcb32 gather ----
// srcb32/baseb32: [13][NN][15].  agg32 out: family-major [fam=t*2+zz][NN][80] u32.
//   zz=0 (c 0..39):  A-word at c,     B-word at 40+c
//   zz=1 (c 40..74): A-word at c-40,  B-word at 36+(c-40) = c-4
__global__ __launch_bounds__(192) void k_agg(const u32* __restrict__ srcb32,
                                             const int* __restrict__ csr,
                                             const int* __restrict__ offs,
                                             const u32* __restrict__ baseb32,
                                             u32* __restrict__ agg32) {
    int q = threadIdx.x;
    if (q >= 188) return;
    int pp = (q < 180) ? (q / 15) : 12;
    int ww = (q < 180) ? (q % 15) : (q - 180);
    const u32* sp = srcb32 + (size_t)pp * NN * 15 + ww;
    const u32* bpp = baseb32 + (size_t)pp * NN * 15 + ww;
    int o0 = 2 * q, o1 = 2 * q + 1;
    bool has1 = o1 < 375;
    int t0 = o0 / 75, c0 = o0 % 75;
    int t1 = has1 ? (o1 / 75) : 0, c1 = has1 ? (o1 % 75) : 0;
    int z0 = (c0 >= 40) ? 1 : 0;
    size_t fb0 = (size_t)(t0 * 2 + z0) * NN * 80;
    int a0o = z0 ? (c0 - 40) : c0;
    int b0o = z0 ? (c0 - 4) : (40 + c0);
    int z1 = (c1 >= 40) ? 1 : 0;
    size_t fb1 = (size_t)(t1 * 2 + z1) * NN * 80;
    int a1o = z1 ? (c1 - 40) : c1;
    int b1o = z1 ? (c1 - 4) : (40 + c1);
    for (int v = blockIdx.x; v < NN; v += gridDim.x) {
        int e0 = offs[v], e1 = offs[v + 1];
        float s0 = 0.f, s1 = 0.f, sq0 = 0.f, sq1 = 0.f;
        float mn0 = 3.4e38f, mn1 = 3.4e38f, mx0 = -3.4e38f, mx1 = -3.4e38f;
        for (int e = e0; e < e1; e++) {
            int s = csr[e];
            u32 w = sp[(size_t)s * 15];
            float x0 = bl2f((u16)(w & 0xffffu)), x1 = bl2f((u16)(w >> 16));
            s0 += x0; sq0 = fmaf(x0, x0, sq0); mn0 = fminf(mn0, x0); mx0 = fmaxf(mx0, x0);
            s1 += x1; sq1 = fmaf(x1, x1, sq1); mn1 = fminf(mn1, x1); mx1 = fmaxf(mx1, x1);
        }
        int deg = e1 - e0;
        u32 bw = bpp[(size_t)v * 15];
        float b0 = bl2f((u16)(bw & 0xffffu)), b1 = bl2f((u16)(bw >> 16));
        float mean0, mean1, mnf0, mnf1, mxf0, mxf1, sd0, sd1;
        if (deg > 0) {
            float im = 1.f / (float)deg;
            float mm0 = s0 * im, mm1 = s1 * im;
            float v0 = fmaxf(fmaf(-mm0, mm0, sq0 * im), 0.f);
            float v1 = fmaxf(fmaf(-mm1, mm1, sq1 * im), 0.f);
            sd0 = sqrtf(v0 + 1e-5f); sd1 = sqrtf(v1 + 1e-5f);
            mean0 = b0 + mm0; mean1 = b1 + mm1;
            mnf0 = b0 + mn0;  mnf1 = b1 + mn1;
            mxf0 = b0 + mx0;  mxf1 = b1 + mx1;
        } else {
            float sde = sqrtf(1e-5f);
            mean0 = mean1 = mnf0 = mnf1 = mxf0 = mxf1 = 0.f;
            sd0 = sd1 = sde;
        }
        u32* fp0 = agg32 + fb0 + (size_t)v * 80;
        fp0[a0o] = pack2(mean0, mnf0);
        fp0[b0o] = pack2(mxf0, sd0);
        if (has1) {
            u32* fp1 = agg32 + fb1 + (size_t)v * 80;
            fp1[a1o] = pack2(mean1, mnf1);
            fp1[b1o] = pack2(mxf1, sd1);
        }
    }
}

// ---- one cq (4 c-columns) of the agg GEMM ----
__device__ __forceinline__ void post_cq(int cq, uint4 A, uint4 B, float amp, float inv,
                                        const float* __restrict__ wq, float acc[15]) {
#pragma unroll
    for (int i = 0; i < 4; i++) {
        int c = cq * 4 + i;
        if (c < 75) {
            u32 wA = (i == 0) ? A.x : (i == 1) ? A.y : (i == 2) ? A.z : A.w;
            u32 wB = (i == 0) ? B.x : (i == 1) ? B.y : (i == 2) ? B.z : B.w;
            float vs[4];
            vs[0] = bl2f((u16)(wA & 0xffffu)); vs[1] = bl2f((u16)(wA >> 16));
            vs[2] = bl2f((u16)(wB & 0xffffu)); vs[3] = bl2f((u16)(wB >> 16));
            const float* wc = wq + c * 180;
#pragma unroll
            for (int s4 = 0; s4 < 4; s4++) {
                float a = vs[s4], aa = a * amp, ai = a * inv;
                const float* wb = wc + s4 * 45;
#pragma unroll
                for (int j = 0; j < 15; j++)
                    acc[j] = fmaf(a, wb[j], fmaf(aa, wb[15 + j], fmaf(ai, wb[30 + j], acc[j])));
            }
        }
    }
}

// ---------------- k_post: agg GEMM over family-major agg32 (dense private reads) ----
__global__ __launch_bounds__(256) void k_post(const int* __restrict__ offs,
                                              const u32* __restrict__ agg32,
                                              const float* __restrict__ wqt_l,
                                              const float* __restrict__ adl_p,
                                              float* __restrict__ tmp0,
                                              float* __restrict__ tmp1) {
    int t = blockIdx.y;
    int zz = blockIdx.z;
    int n = blockIdx.x * 256 + threadIdx.x;
    if (n >= NN) return;
    float adl = adl_p[0];
    int deg = offs[n + 1] - offs[n];
    float dc = (float)(deg > 0 ? deg : 1);
    float amp = log1pf(dc) / adl;
    float inv = 1.f / amp;
    const float* wq = wqt_l + (size_t)t * 13500;
    const uint4* ap = (const uint4*)(agg32 + ((size_t)(t * 2 + zz) * NN + n) * 80);
    float acc[15];
#pragma unroll
    for (int j = 0; j < 15; j++) acc[j] = 0.f;
    if (zz == 0) {
        uint4 A[10], B[10];
#pragma unroll
        for (int g = 0; g < 10; g++) { A[g] = ap[g]; B[g] = ap[10 + g]; }
#pragma unroll
        for (int g = 0; g < 10; g++) post_cq(g, A[g], B[g], amp, inv, wq, acc);
#pragma unroll
        for (int j = 0; j < 15; j++) tmp0[(size_t)(t * 15 + j) * NN + n] = acc[j];
    } else {
        uint4 A[9], B[9];
#pragma unroll
        for (int g = 0; g < 9; g++) { A[g] = ap[g]; B[g] = ap[9 + g]; }
#pragma unroll
        for (int g = 0; g < 9; g++) post_cq(10 + g, A[g], B[g], amp, inv, wq, acc);
#pragma unroll
        for (int j = 0; j < 15; j++) tmp1[(size_t)(t * 15 + j) * NN + n] = acc[j];
    }
}

// ---------------- k_lin2: 1D XCD-coherent grid, b = p*LIN_XS + x ----
__global__ __launch_bounds__(256) void k_lin2(const float* __restrict__ tmp0,
                                              const float* __restrict__ tmp1,
                                              const float* __restrict__ hT,
                                              const float* __restrict__ Wl,
                                              const float* __restrict__ Mf_l,
                                              const float* __restrict__ bladj,
                                              float* __restrict__ zF,
                                              float* __restrict__ bsum,
                                              float* __restrict__ bsq) {
    __shared__ __align__(16) float wl[75][16];
    __shared__ __align__(16) float wm[75][16];
    __shared__ float red1[4][15], red2[4][15];
    int b = blockIdx.x;
    int p = b / LIN_XS;
    int x = b - p * LIN_XS;
    for (int idx = threadIdx.x; idx < 75 * 15; idx += 256) {
        int k = idx / 15, j = idx % 15;
        wl[k][j] = Wl[k * 75 + p * 15 + j];
        wm[k][j] = Mf_l[k * 75 + p * 15 + j];
    }
    __syncthreads();
    int n = x * 256 + threadIdx.x;
    bool valid = n < NN;
    int nc = valid ? n : NN - 1;
    float acc[15];
#pragma unroll
    for (int j = 0; j < 15; j++) acc[j] = bladj[p * 15 + j];
    for (int k = 0; k < 75; k++) {
        float a = tmp0[(size_t)k * NN + nc] + tmp1[(size_t)k * NN + nc];
        float h = hT[(size_t)k * NN + nc];
        float4 w0 = *(const float4*)&wl[k][0];
        float4 w1 = *(const float4*)&wl[k][4];
        float4 w2 = *(const float4*)&wl[k][8];
        float4 w3 = *(const float4*)&wl[k][12];
        float4 m0 = *(const float4*)&wm[k][0];
        float4 m1 = *(const float4*)&wm[k][4];
        float4 m2 = *(const float4*)&wm[k][8];
        float4 m3 = *(const float4*)&wm[k][12];
        acc[0]  = fmaf(h, m0.x, fmaf(a, w0.x, acc[0]));
        acc[1]  = fmaf(h, m0.y, fmaf(a, w0.y, acc[1]));
        acc[2]  = fmaf(h, m0.z, fmaf(a, w0.z, acc[2]));
        acc[3]  = fmaf(h, m0.w, fmaf(a, w0.w, acc[3]));
        acc[4]  = fmaf(h, m1.x, fmaf(a, w1.x, acc[4]));
        acc[5]  = fmaf(h, m1.y, fmaf(a, w1.y, acc[5]));
        acc[6]  = fmaf(h, m1.z, fmaf(a, w1.z, acc[6]));
        acc[7]  = fmaf(h, m1.w, fmaf(a, w1.w, acc[7]));
        acc[8]  = fmaf(h, m2.x, fmaf(a, w2.x, acc[8]));
        acc[9]  = fmaf(h, m2.y, fmaf(a, w2.y, acc[9]));
        acc[10] = fmaf(h, m2.z, fmaf(a, w2.z, acc[10]));
        acc[11] = fmaf(h, m2.w, fmaf(a, w2.w, acc[11]));
        acc[12] = fmaf(h, m3.x, fmaf(a, w3.x, acc[12]));
        acc[13] = fmaf(h, m3.y, fmaf(a, w3.y, acc[13]));
        acc[14] = fmaf(h, m3.z, fmaf(a, w3.z, acc[14]));
    }
    if (valid) {
#pragma unroll
        for (int j = 0; j < 15; j++)
            zF[(size_t)(p * 15 + j) * NN + n] = acc[j];
    }
    float s[15], ss[15];
#pragma unroll
    for (int i = 0; i < 15; i++) {
        float a = valid ? acc[i] : 0.f;
        s[i] = a; ss[i] = a * a;
    }
    for (int d = 32; d > 0; d >>= 1) {
#pragma unroll
        for (int i = 0; i < 15; i++) {
            s[i] += __shfl_down(s[i], d);
            ss[i] += __shfl_down(ss[i], d);
        }
    }
    int wave = threadIdx.x >> 6, lane = threadIdx.x & 63;
    if (lane == 0) {
#pragma unroll
        for (int i = 0; i < 15; i++) { red1[wave][i] = s[i]; red2[wave][i] = ss[i]; }
    }
    __syncthreads();
    if (threadIdx.x < 15) {
        int i = threadIdx.x;
        float a = red1[0][i] + red1[1][i] + red1[2][i] + red1[3][i];
        float b2 = red2[0][i] + red2[1][i] + red2[2][i] + red2[3][i];
        atomicAdd(&bsum[p * 15 + i], a);
        atomicAdd(&bsq[p * 15 + i], b2);
    }
}

// ---------------- k_bn2: BN + ReLU, zF -> hT f32 + hB bf16 ----------
__global__ __launch_bounds__(256) void k_bn2(const float* __restrict__ zF,
                                             const float* __restrict__ bsum,
                                             const float* __restrict__ bsq,
                                             const float* __restrict__ g,
                                             const float* __restrict__ b,
                                             float* __restrict__ hT,
                                             u32* __restrict__ hB) {
    int n = blockIdx.x * 256 + threadIdx.x;
    if (n >= NN) return;
    float buf[80];
    for (int c = 0; c < 75; c++) {
        float mu = bsum[c] * (1.f / NN);
        float var = bsq[c] * (1.f / NN) - mu * mu;
        float sc = g[c] * rsqrtf(var + 1e-5f);
        float v = (zF[(size_t)c * NN + n] - mu) * sc + b[c];
        float r = v > 0.f ? v : 0.f;
        buf[c] = r;
        hT[(size_t)c * NN + n] = r;
    }
#pragma unroll
    for (int c = 75; c < 80; c++) buf[c] = 0.f;
    uint4* bp4 = (uint4*)(hB + (size_t)n * 40);
#pragma unroll
    for (int w = 0; w < 10; w++)
        bp4[w] = make_uint4(pack2(buf[8 * w], buf[8 * w + 1]), pack2(buf[8 * w + 2], buf[8 * w + 3]),
                            pack2(buf[8 * w + 4], buf[8 * w + 5]), pack2(buf[8 * w + 6], buf[8 * w + 7]));
}

// ---------------- MLP head ----------------
__global__ __launch_bounds__(256) void k_mlp1(const float* __restrict__ hT,
                                              const float* __restrict__ alpha,
                                              const int* __restrict__ batch,
                                              const float* __restrict__ w1,
                                              const float* __restrict__ b1,
                                              float* __restrict__ t1) {
    int n = blockIdx.x * 256 + threadIdx.x;
    if (n >= NN) return;
    float acc[50];
#pragma unroll
    for (int j = 0; j < 50; j++) acc[j] = b1[j];
    for (int k = 0; k < 75; k++) {
        float in = hT[(size_t)k * NN + n];
        const float* wr = w1 + k * 50;
#pragma unroll
        for (int j = 0; j < 50; j++) acc[j] = fmaf(in, wr[j], acc[j]);
    }
    float a = alpha[batch[n]];
    const float* wr = w1 + 75 * 50;
#pragma unroll
    for (int j = 0; j < 50; j++) {
        float v = fmaf(a, wr[j], acc[j]);
        t1[(size_t)j * NN + n] = v > 0.f ? v : 0.f;
    }
}

__global__ void k_mlp2(const float* __restrict__ t1, const float* __restrict__ w2,
                       const float* __restrict__ b2, const float* __restrict__ w3,
                       const float* __restrict__ b3, const float* __restrict__ noise,
                       const float* __restrict__ x, float* __restrict__ out) {
    int n = blockIdx.x * 256 + threadIdx.x;
    if (n >= NN) return;
    float tr[50];
#pragma unroll
    for (int k = 0; k < 50; k++) tr[k] = t1[(size_t)k * NN + n];
    float y = b3[0];
#pragma unroll
    for (int k2 = 0; k2 < 25; k2++) {
        float acc = b2[k2];
#pragma unroll
        for (int k = 0; k < 50; k++) acc = fmaf(tr[k], w2[k * 25 + k2], acc);
        acc = acc > 0.f ? acc : 0.f;
        y = fmaf(acc, w3[k2], y);
    }
    float z = y + noise[n];
    float s = 1.f / (1.f + expf(-z));
    out[n] = s;
    out[NN + n] = x[2 * n];
}

extern "C" void kernel_launch(void* const* d_in, const int* in_sizes, int n_in,
                              void* d_out, int out_size, void* d_ws, size_t ws_size,
                              hipStream_t stream) {
    const float* x      = (const float*)d_in[0];
    const float* alpha  = (const float*)d_in[1];
    const int*   ei     = (const int*)d_in[2];
    const int*   batch  = (const int*)d_in[3];
    const float* noise  = (const float*)d_in[4];
    const float* adl    = (const float*)d_in[5];
    const float* pre_w  = (const float*)d_in[6];
    const float* pre_b  = (const float*)d_in[7];
    const float* W_pre  = (const float*)d_in[8];
    const float* b_pre  = (const float*)d_in[9];
    const float* W_post = (const float*)d_in[10];
    const float* b_post = (const float*)d_in[11];
    const float* W_lin  = (const float*)d_in[12];
    const float* b_lin  = (const float*)d_in[13];
    const float* bn_g   = (const float*)d_in[14];
    const float* bn_b   = (const float*)d_in[15];
    const float* mw1    = (const float*)d_in[16];
    const float* mb1    = (const float*)d_in[17];
    const float* mw2    = (const float*)d_in[18];
    const float* mb2    = (const float*)d_in[19];
    const float* mw3    = (const float*)d_in[20];
    const float* mb3    = (const float*)d_in[21];
    (void)in_sizes; (void)n_in; (void)out_size; (void)ws_size;

    char* ws = (char*)d_ws;
    size_t off = 0;
    auto alloc = [&](size_t bytes) -> char* {
        char* p = ws + off;
        off += (bytes + 255) & ~((size_t)255);
        return p;
    };
    float* hT     = (float*)alloc((size_t)75 * NN * 4);        //  9.0 MB (col-major h)
    u32*   hB     = (u32*)alloc((size_t)NN * 40 * 4);          //  4.8 MB
    float* zF     = (float*)alloc((size_t)75 * NN * 4);        //  9.0 MB
    float* tmp0   = (float*)alloc((size_t)75 * NN * 4);        //  9.0 MB
    float* tmp1   = (float*)alloc((size_t)75 * NN * 4);        //  9.0 MB
    u32*   agg32  = (u32*)alloc((size_t)10 * NN * 80 * 4);     // 96.0 MB (family-major)
    u32*   baseb32= (u32*)alloc((size_t)13 * NN * 15 * 4);     // 23.4 MB (chunk-major)
    u32*   srcb32 = (u32*)alloc((size_t)13 * NN * 15 * 4);     // 23.4 MB (chunk-major)
    float* wqt    = (float*)alloc((size_t)270000 * 4);         //  1.1 MB
    float* Mf     = (float*)alloc((size_t)22500 * 4);          //  90 KB
    float* bladj  = (float*)alloc(300 * 4);
    int*   cnt    = (int*)alloc((size_t)NN * 4);
    int*   offs   = (int*)alloc((size_t)(NN + 1) * 4);
    int*   fill   = (int*)alloc((size_t)NN * 4);
    int*   csr    = (int*)alloc((size_t)EE * 4);
    float* bnsum  = (float*)alloc(4 * 75 * 4);
    float* bnsq   = (float*)alloc(4 * 75 * 4);

    hipMemsetAsync(cnt, 0, (size_t)NN * 4, stream);
    hipMemsetAsync(fill, 0, (size_t)NN * 4, stream);
    hipMemsetAsync(bnsum, 0, 4 * 75 * 4, stream);
    hipMemsetAsync(bnsq, 0, 4 * 75 * 4, stream);

    const int* src = ei;
    const int* dst = ei + EE;
    int eb = (EE + 255) / 256;
    int nb = (NN + 255) / 256;

    k_count<<<eb, 256, 0, stream>>>(dst, cnt);
    k_scan<<<1, 1024, 0, stream>>>(cnt, offs);
    k_scatter<<<eb, 256, 0, stream>>>(src, dst, offs, fill, csr);
    k_pre<<<nb, 256, 0, stream>>>(x, pre_w, pre_b, hT, hB);
    k_wqt<<<(270000 + 255) / 256, 256, 0, stream>>>(W_post, wqt);
    k_badj<<<2, 256, 0, stream>>>(b_lin, b_post, W_lin, bladj);
    k_wm<<<(22500 + 255) / 256, 256, 0, stream>>>(W_post, W_lin, Mf);

    for (int l = 0; l < 4; l++) {
        const float* Wp  = W_pre + (size_t)l * 5 * 150 * 75;
        const float* bp  = b_pre + l * 375;
        const float* wqtl= wqt + (size_t)l * 67500;
        const float* Wl  = W_lin + l * 75 * 75;
        k_base<<<13 * BASE_XS, 256, 0, stream>>>(hB, Wp, bp, baseb32, srcb32);
        k_agg<<<4096, 192, 0, stream>>>(srcb32, csr, offs, baseb32, agg32);
        k_post<<<dim3(nb, 5, 2), 256, 0, stream>>>(offs, agg32, wqtl, adl, tmp0, tmp1);
        k_lin2<<<5 * LIN_XS, 256, 0, stream>>>(tmp0, tmp1, hT, Wl, Mf + l * 5625,
                                               bladj + l * 75, zF,
                                               bnsum + l * 75, bnsq + l * 75);
        k_bn2<<<nb, 256, 0, stream>>>(zF, bnsum + l * 75, bnsq + l * 75,
                                      bn_g + l * 75, bn_b + l * 75, hT, hB);
    }

    float* t1 = tmp0;
    k_mlp1<<<nb, 256, 0, stream>>>(hT, alpha, batch, mw1, mb1, t1);
    k_mlp2<<<nb, 256, 0, stream>>>(t1, mw2, mb2, mw3, mb3, noise, x, (float*)d_out);
}

// Round 15
// 1453.253 us; speedup vs baseline: 1.0434x; 1.0434x over previous
//
#include <hip/hip_runtime.h>
#include <hip/hip_bf16.h>
#include <cstdint>
#include <cstddef>

#define NN 30000
#define EE 150000
#define BASE_XS 120 // k_base x-blocks per chunk-p (>= ceil(30000/256)=118, mult of 8)
#define LIN_XS 120  // k_lin2 x-blocks per p (>= ceil(30000/256)=118, mult of 8)

using u16 = unsigned short;
using u32 = unsigned int;

__device__ __forceinline__ float bl2f(u16 u) { return __uint_as_float(((u32)u) << 16); }
__device__ __forceinline__ u16 f2bl(float f) {
    u32 x = __float_as_uint(f);
    return (u16)((x + 0x7fffu + ((x >> 16) & 1u)) >> 16);
}
__device__ __forceinline__ u32 pack2(float a, float b) {
    return (u32)f2bl(a) | ((u32)f2bl(b) << 16);
}

// ---------------- CSR build ----------------
__global__ void k_count(const int* __restrict__ dst, int* __restrict__ cnt) {
    int e = blockIdx.x * 256 + threadIdx.x;
    if (e < EE) atomicAdd(&cnt[dst[e]], 1);
}

__global__ void k_scan(const int* __restrict__ cnt, int* __restrict__ offs) {
    __shared__ int ss[1024];
    int t = threadIdx.x;
    int base = t * 30;
    int s = 0;
    for (int i = 0; i < 30; i++) { int idx = base + i; if (idx < NN) s += cnt[idx]; }
    ss[t] = s; __syncthreads();
    for (int off = 1; off < 1024; off <<= 1) {
        int v = (t >= off) ? ss[t - off] : 0;
        __syncthreads();
        ss[t] += v;
        __syncthreads();
    }
    int run = (t == 0) ? 0 : ss[t - 1];
    for (int i = 0; i < 30; i++) {
        int idx = base + i;
        if (idx < NN) { offs[idx] = run; run += cnt[idx]; }
    }
    if (t == 1023) offs[NN] = run;
}

__global__ void k_scatter(const int* __restrict__ src, const int* __restrict__ dst,
                          const int* __restrict__ offs, int* __restrict__ fill,
                          int* __restrict__ csr) {
    int e = blockIdx.x * 256 + threadIdx.x;
    if (e < EE) {
        int d = dst[e];
        int p = offs[d] + atomicAdd(&fill[d], 1);
        csr[p] = src[e];
    }
}

// ---------------- k_wqt: transpose agg-part of W_post into c-major layout --------
__global__ void k_wqt(const float* __restrict__ W_post, float* __restrict__ wqt) {
    int idx = blockIdx.x * 256 + threadIdx.x;
    if (idx >= 270000) return;
    int j = idx % 15;
    int grp = (idx / 15) % 3;
    int s4 = (idx / 45) % 4;
    int c = (idx / 180) % 75;
    int lt = idx / 13500;
    wqt[idx] = W_post[(size_t)lt * 975 * 15 + (size_t)(75 + grp * 300 + s4 * 75 + c) * 15 + j];
}

// ---------------- k_badj: bladj[l][c] = bl[c] + sum_k bq[k]*Wl[k][c]  (exact fold) ----
__global__ void k_badj(const float* __restrict__ b_lin, const float* __restrict__ b_post,
                       const float* __restrict__ W_lin, float* __restrict__ bladj) {
    int idx = blockIdx.x * 256 + threadIdx.x;
    if (idx >= 300) return;
    int l = idx / 75, c = idx % 75;
    float a = b_lin[l * 75 + c];
    const float* bq = b_post + l * 75;
    const float* Wl = W_lin + (size_t)l * 75 * 75;
    for (int k = 0; k < 75; k++) a = fmaf(bq[k], Wl[k * 75 + c], a);
    bladj[idx] = a;
}

// ---------------- k_wm: fold x-part through W_lin ----------------
__global__ void k_wm(const float* __restrict__ W_post, const float* __restrict__ W_lin,
                     float* __restrict__ Mf) {
    int idx = blockIdx.x * 256 + threadIdx.x;
    if (idx >= 22500) return;
    int l = idx / 5625;
    int c = (idx / 75) % 75;
    int o = idx % 75;
    const float* Wq = W_post + (size_t)l * 5 * 975 * 15;
    const float* Wl = W_lin + (size_t)l * 75 * 75;
    float a = 0.f;
    for (int t5 = 0; t5 < 5; t5++) {
        const float* wr = Wq + (size_t)t5 * 975 * 15 + (size_t)c * 15;
        const float* lr = Wl + (size_t)(t5 * 15) * 75 + o;
#pragma unroll
        for (int j = 0; j < 15; j++) a = fmaf(wr[j], lr[(size_t)j * 75], a);
    }
    Mf[idx] = a;
}

// ---------------- pre linear: hT[75][NN] f32 (col-major) + hB[n][40] bf16 pairs ------
__global__ void k_pre(const float* __restrict__ x, const float* __restrict__ pw,
                      const float* __restrict__ pb, float* __restrict__ hT,
                      u32* __restrict__ hB) {
    int n = blockIdx.x * 256 + threadIdx.x;
    if (n >= NN) return;
    float x0 = x[2 * n], x1 = x[2 * n + 1];
    float buf[80];
#pragma unroll
    for (int c = 0; c < 80; c++)
        buf[c] = (c < 75) ? fmaf(x0, pw[c], fmaf(x1, pw[75 + c], pb[c])) : 0.f;
#pragma unroll
    for (int c = 0; c < 75; c++)
        hT[(size_t)c * NN + n] = buf[c];
    uint4* bp4 = (uint4*)(hB + (size_t)n * 40);
#pragma unroll
    for (int w = 0; w < 10; w++)
        bp4[w] = make_uint4(pack2(buf[8 * w], buf[8 * w + 1]), pack2(buf[8 * w + 2], buf[8 * w + 3]),
                            pack2(buf[8 * w + 4], buf[8 * w + 5]), pack2(buf[8 * w + 6], buf[8 * w + 7]));
}

// ---- unpack helper: float k (0..7) from uint4 of bf16 pairs ----
__device__ __forceinline__ float upk(const uint4& a, int k) {
    u32 u = (k < 2) ? a.x : (k < 4) ? a.y : (k < 6) ? a.z : a.w;
    return __uint_as_float((k & 1) ? (u & 0xffff0000u) : (u << 16));
}

// ---- single-row inner: 1 row x 30 outputs, uniform weights (wA,wB 15-col slices) ----
__device__ __forceinline__ void gemm30s(const uint4* __restrict__ h,
                                        const float* __restrict__ wA,
                                        const float* __restrict__ wB,
                                        float acc[30]) {
    for (int fq = 0; fq < 9; fq++) {
        uint4 a0 = h[fq];
#pragma unroll
        for (int k = 0; k < 8; k++) {
            float i0 = upk(a0, k);
            const float* ra = wA + (fq * 8 + k) * 75;
            const float* rb = wB + (fq * 8 + k) * 75;
#pragma unroll
            for (int j = 0; j < 15; j++) acc[j] = fmaf(i0, ra[j], acc[j]);
#pragma unroll
            for (int j = 0; j < 15; j++) acc[15 + j] = fmaf(i0, rb[j], acc[15 + j]);
        }
    }
    uint4 a0 = h[9];
#pragma unroll
    for (int k = 0; k < 3; k++) {
        float i0 = upk(a0, k);
        const float* ra = wA + (72 + k) * 75;
        const float* rb = wB + (72 + k) * 75;
#pragma unroll
        for (int j = 0; j < 15; j++) acc[j] = fmaf(i0, ra[j], acc[j]);
#pragma unroll
        for (int j = 0; j < 15; j++) acc[15 + j] = fmaf(i0, rb[j], acc[15 + j]);
    }
}

// chunk p (0..12) -> weight slice pointers (15-col groups A and B)
__device__ __forceinline__ void chunk_w(int p, const float* Wp, int half_off,
                                        const float** wA, const float** wB, bool* full) {
    int cg = p * 2;
    int tA = cg / 5, cA = (cg % 5) * 15;
    *full = p < 12;
    int cg1 = *full ? cg + 1 : cg;
    int tB = cg1 / 5, cB = (cg1 % 5) * 15;
    *wA = Wp + ((size_t)tA * 150 + half_off) * 75 + cA;
    *wB = Wp + ((size_t)tB * 150 + half_off) * 75 + cB;
}

// ---- pack 30 accs into a padded 16-u32 row (64 B = 1 cache line), 4 uint4 stores ----
__device__ __forceinline__ void pack_row16(u32* rp, const float* a, bool full) {
    u32 t[16];
    if (full) {
#pragma unroll
        for (int w = 0; w < 15; w++) t[w] = pack2(a[2 * w], a[2 * w + 1]);
    } else {
#pragma unroll
        for (int w = 0; w < 7; w++) t[w] = pack2(a[2 * w], a[2 * w + 1]);
        t[7] = pack2(a[14], 0.f);
#pragma unroll
        for (int w = 8; w < 15; w++) t[w] = 0u;
    }
    t[15] = 0u;
    uint4* q = (uint4*)rp;
    q[0] = make_uint4(t[0], t[1], t[2], t[3]);
    q[1] = make_uint4(t[4], t[5], t[6], t[7]);
    q[2] = make_uint4(t[8], t[9], t[10], t[11]);
    q[3] = make_uint4(t[12], t[13], t[14], t[15]);
}

// ---------------- k_base: 1 node/thread x 13 chunks, BOTH halves, padded chunk-major --
// baseb32/srcb32 layout: [13][NN][16] u32 -> each thread writes exactly one 64 B
// cache line via 4 aligned uint4 stores; wave instruction = 1024 B of FULL lines.
// No partial-line RMW/RFO at any occupancy -> 1560 blocks (~6 waves/SIMD).
__global__ __launch_bounds__(256) void k_base(const u32* __restrict__ hB,
                                              const float* __restrict__ Wp,
                                              const float* __restrict__ bp,
                                              u32* __restrict__ baseb32,
                                              u32* __restrict__ srcb32) {
    int b = blockIdx.x;
    int p = b / BASE_XS;
    int xx = b - p * BASE_XS;
    int n = xx * 256 + threadIdx.x;
    if (n >= NN) return;
    uint4 h[10];
    const uint4* hp = (const uint4*)(hB + (size_t)n * 40);
#pragma unroll
    for (int w = 0; w < 10; w++) h[w] = hp[w];
    int o0 = p * 30;
    size_t slot = ((size_t)p * NN + n) * 16;
    {   // dst half (with bias)
        const float *wA, *wB; bool full;
        chunk_w(p, Wp, 0, &wA, &wB, &full);
        float acc[30];
#pragma unroll
        for (int j = 0; j < 15; j++) acc[j] = bp[o0 + j];
#pragma unroll
        for (int j = 0; j < 15; j++) acc[15 + j] = full ? bp[o0 + 15 + j] : 0.f;
        gemm30s(h, wA, wB, acc);
        pack_row16(baseb32 + slot, acc, full);
    }
    {   // src half (no bias)
        const float *wA, *wB; bool full;
        chunk_w(p, Wp, 75, &wA, &wB, &full);
        float acc[30];
#pragma unroll
        for (int j = 0; j < 30; j++) acc[j] = 0.f;
        gemm30s(h, wA, wB, acc);
        pack_row16(srcb32 + slot, acc, full);
    }
}

// ---------------- k_agg: per-node stats via padded chunk-major srcb32 gather ----
// srcb32/baseb32: [13][NN][16].  agg32 out: family-major [fam=t*2+zz][NN][80] u32.
//   zz=0 (c 0..39):  A-word at c,     B-word at 40+c
//   zz=1 (c 40..74): A-word at c-40,  B-word at 36+(c-40) = c-4
__global__ __launch_bounds__(192) void k_agg(const u32* __restrict__ srcb32,
                                             const int* __restrict__ csr,
                                             const int* __restrict__ offs,
                                             const u32* __restrict__ baseb32,
                                             u32* __restrict__ agg32) {
    int q = threadIdx.x;
    if (q >= 188) return;
    int pp = (q < 180) ? (q / 15) : 12;
    int ww = (q < 180) ? (q % 15) : (q - 180);
    const u32* sp = srcb32 + (size_t)pp * NN * 16 + ww;
    const u32* bpp = baseb32 + (size_t)pp * NN * 16 + ww;
    int o0 = 2 * q, o1 = 2 * q + 1;
    bool has1 = o1 < 375;
    int t0 = o0 / 75, c0 = o0 % 75;
    int t1 = has1 ? (o1 / 75) : 0, c1 = has1 ? (o1 % 75) : 0;
    int z0 = (c0 >= 40) ? 1 : 0;
    size_t fb0 = (size_t)(t0 * 2 + z0) * NN * 80;
    int a0o = z0 ? (c0 - 40) : c0;
    int b0o = z0 ? (c0 - 4) : (40 + c0);
    int z1 = (c1 >= 40) ? 1 : 0;
    size_t fb1 = (size_t)(t1 * 2 + z1) * NN * 80;
    int a1o = z1 ? (c1 - 40) : c1;
    int b1o = z1 ? (c1 - 4) : (40 + c1);
    for (int v = blockIdx.x; v < NN; v += gridDim.x) {
        int e0 = offs[v], e1 = offs[v + 1];
        float s0 = 0.f, s1 = 0.f, sq0 = 0.f, sq1 = 0.f;
        float mn0 = 3.4e38f, mn1 = 3.4e38f, mx0 = -3.4e38f, mx1 = -3.4e38f;
        for (int e = e0; e < e1; e++) {
            int s = csr[e];
            u32 w = sp[(size_t)s * 16];
            float x0 = bl2f((u16)(w & 0xffffu)), x1 = bl2f((u16)(w >> 16));
            s0 += x0; sq0 = fmaf(x0, x0, sq0); mn0 = fminf(mn0, x0); mx0 = fmaxf(mx0, x0);
            s1 += x1; sq1 = fmaf(x1, x1, sq1); mn1 = fminf(mn1, x1); mx1 = fmaxf(mx1, x1);
        }
        int deg = e1 - e0;
        u32 bw = bpp[(size_t)v * 16];
        float b0 = bl2f((u16)(bw & 0xffffu)), b1 = bl2f((u16)(bw >> 16));
        float mean0, mean1, mnf0, mnf1, mxf0, mxf1, sd0, sd1;
        if (deg > 0) {
            float im = 1.f / (float)deg;
            float mm0 = s0 * im, mm1 = s1 * im;
            float v0 = fmaxf(fmaf(-mm0, mm0, sq0 * im), 0.f);
            float v1 = fmaxf(fmaf(-mm1, mm1, sq1 * im), 0.f);
            sd0 = sqrtf(v0 + 1e-5f); sd1 = sqrtf(v1 + 1e-5f);
            mean0 = b0 + mm0; mean1 = b1 + mm1;
            mnf0 = b0 + mn0;  mnf1 = b1 + mn1;
            mxf0 = b0 + mx0;  mxf1 = b1 + mx1;
        } else {
            float sde = sqrtf(1e-5f);
            mean0 = mean1 = mnf0 = mnf1 = mxf0 = mxf1 = 0.f;
            sd0 = sd1 = sde;
        }
        u32* fp0 = agg32 + fb0 + (size_t)v * 80;
        fp0[a0o] = pack2(mean0, mnf0);
        fp0[b0o] = pack2(mxf0, sd0);
        if (has1) {
            u32* fp1 = agg32 + fb1 + (size_t)v * 80;
            fp1[a1o] = pack2(mean1, mnf1);
            fp1[b1o] = pack2(mxf1, sd1);
        }
    }
}

// ---- one cq (4 c-columns) of the agg GEMM ----
__device__ __forceinline__ void post_cq(int cq, uint4 A, uint4 B, float amp, float inv,
                                        const float* __restrict__ wq, float acc[15]) {
#pragma unroll
    for (int i = 0; i < 4; i++) {
        int c = cq * 4 + i;
        if (c < 75) {
            u32 wA = (i == 0) ? A.x : (i == 1) ? A.y : (i == 2) ? A.z : A.w;
            u32 wB = (i == 0) ? B.x : (i == 1) ? B.y : (i == 2) ? B.z : B.w;
            float vs[4];
            vs[0] = bl2f((u16)(wA & 0xffffu)); vs[1] = bl2f((u16)(wA >> 16));
            vs[2] = bl2f((u16)(wB & 0xffffu)); vs[3] = bl2f((u16)(wB >> 16));
            const float* wc = wq + c * 180;
#pragma unroll
            for (int s4 = 0; s4 < 4; s4++) {
                float a = vs[s4], aa = a * amp, ai = a * inv;
                const float* wb = wc + s4 * 45;
#pragma unroll
                for (int j = 0; j < 15; j++)
                    acc[j] = fmaf(a, wb[j], fmaf(aa, wb[15 + j], fmaf(ai, wb[30 + j], acc[j])));
            }
        }
    }
}

// ---------------- k_post: agg GEMM over family-major agg32 (dense private reads) ----
__global__ __launch_bounds__(256) void k_post(const int* __restrict__ offs,
                                              const u32* __restrict__ agg32,
                                              const float* __restrict__ wqt_l,
                                              const float* __restrict__ adl_p,
                                              float* __restrict__ tmp0,
                                              float* __restrict__ tmp1) {
    int t = blockIdx.y;
    int zz = blockIdx.z;
    int n = blockIdx.x * 256 + threadIdx.x;
    if (n >= NN) return;
    float adl = adl_p[0];
    int deg = offs[n + 1] - offs[n];
    float dc = (float)(deg > 0 ? deg : 1);
    float amp = log1pf(dc) / adl;
    float inv = 1.f / amp;
    const float* wq = wqt_l + (size_t)t * 13500;
    const uint4* ap = (const uint4*)(agg32 + ((size_t)(t * 2 + zz) * NN + n) * 80);
    float acc[15];
#pragma unroll
    for (int j = 0; j < 15; j++) acc[j] = 0.f;
    if (zz == 0) {
        uint4 A[10], B[10];
#pragma unroll
        for (int g = 0; g < 10; g++) { A[g] = ap[g]; B[g] = ap[10 + g]; }
#pragma unroll
        for (int g = 0; g < 10; g++) post_cq(g, A[g], B[g], amp, inv, wq, acc);
#pragma unroll
        for (int j = 0; j < 15; j++) tmp0[(size_t)(t * 15 + j) * NN + n] = acc[j];
    } else {
        uint4 A[9], B[9];
#pragma unroll
        for (int g = 0; g < 9; g++) { A[g] = ap[g]; B[g] = ap[9 + g]; }
#pragma unroll
        for (int g = 0; g < 9; g++) post_cq(10 + g, A[g], B[g], amp, inv, wq, acc);
#pragma unroll
        for (int j = 0; j < 15; j++) tmp1[(size_t)(t * 15 + j) * NN + n] = acc[j];
    }
}

// ---------------- k_lin2: 1D XCD-coherent grid, b = p*LIN_XS + x ----
__global__ __launch_bounds__(256) void k_lin2(const float* __restrict__ tmp0,
                                              const float* __restrict__ tmp1,
                                              const float* __restrict__ hT,
                                              const float* __restrict__ Wl,
                                              const float* __restrict__ Mf_l,
                                              const float* __restrict__ bladj,
                                              float* __restrict__ zF,
                                              float* __restrict__ bsum,
                                              float* __restrict__ bsq) {
    __shared__ __align__(16) float wl[75][16];
    __shared__ __align__(16) float wm[75][16];
    __shared__ float red1[4][15], red2[4][15];
    int b = blockIdx.x;
    int p = b / LIN_XS;
    int x = b - p * LIN_XS;
    for (int idx = threadIdx.x; idx < 75 * 15; idx += 256) {
        int k = idx / 15, j = idx % 15;
        wl[k][j] = Wl[k * 75 + p * 15 + j];
        wm[k][j] = Mf_l[k * 75 + p * 15 + j];
    }
    __syncthreads();
    int n = x * 256 + threadIdx.x;
    bool valid = n < NN;
    int nc = valid ? n : NN - 1;
    float acc[15];
#pragma unroll
    for (int j = 0; j < 15; j++) acc[j] = bladj[p * 15 + j];
    for (int k = 0; k < 75; k++) {
        float a = tmp0[(size_t)k * NN + nc] + tmp1[(size_t)k * NN + nc];
        float h = hT[(size_t)k * NN + nc];
        float4 w0 = *(const float4*)&wl[k][0];
        float4 w1 = *(const float4*)&wl[k][4];
        float4 w2 = *(const float4*)&wl[k][8];
        float4 w3 = *(const float4*)&wl[k][12];
        float4 m0 = *(const float4*)&wm[k][0];
        float4 m1 = *(const float4*)&wm[k][4];
        float4 m2 = *(const float4*)&wm[k][8];
        float4 m3 = *(const float4*)&wm[k][12];
        acc[0]  = fmaf(h, m0.x, fmaf(a, w0.x, acc[0]));
        acc[1]  = fmaf(h, m0.y, fmaf(a, w0.y, acc[1]));
        acc[2]  = fmaf(h, m0.z, fmaf(a, w0.z, acc[2]));
        acc[3]  = fmaf(h, m0.w, fmaf(a, w0.w, acc[3]));
        acc[4]  = fmaf(h, m1.x, fmaf(a, w1.x, acc[4]));
        acc[5]  = fmaf(h, m1.y, fmaf(a, w1.y, acc[5]));
        acc[6]  = fmaf(h, m1.z, fmaf(a, w1.z, acc[6]));
        acc[7]  = fmaf(h, m1.w, fmaf(a, w1.w, acc[7]));
        acc[8]  = fmaf(h, m2.x, fmaf(a, w2.x, acc[8]));
        acc[9]  = fmaf(h, m2.y, fmaf(a, w2.y, acc[9]));
        acc[10] = fmaf(h, m2.z, fmaf(a, w2.z, acc[10]));
        acc[11] = fmaf(h, m2.w, fmaf(a, w2.w, acc[11]));
        acc[12] = fmaf(h, m3.x, fmaf(a, w3.x, acc[12]));
        acc[13] = fmaf(h, m3.y, fmaf(a, w3.y, acc[13]));
        acc[14] = fmaf(h, m3.z, fmaf(a, w3.z, acc[14]));
    }
    if (valid) {
#pragma unroll
        for (int j = 0; j < 15; j++)
            zF[(size_t)(p * 15 + j) * NN + n] = acc[j];
    }
    float s[15], ss[15];
#pragma unroll
    for (int i = 0; i < 15; i++) {
        float a = valid ? acc[i] : 0.f;
        s[i] = a; ss[i] = a * a;
    }
    for (int d = 32; d > 0; d >>= 1) {
#pragma unroll
        for (int i = 0; i < 15; i++) {
            s[i] += __shfl_down(s[i], d);
            ss[i] += __shfl_down(ss[i], d);
        }
    }
    int wave = threadIdx.x >> 6, lane = threadIdx.x & 63;
    if (lane == 0) {
#pragma unroll
        for (int i = 0; i < 15; i++) { red1[wave][i] = s[i]; red2[wave][i] = ss[i]; }
    }
    __syncthreads();
    if (threadIdx.x < 15) {
        int i = threadIdx.x;
        float a = red1[0][i] + red1[1][i] + red1[2][i] + red1[3][i];
        float b2 = red2[0][i] + red2[1][i] + red2[2][i] + red2[3][i];
        atomicAdd(&bsum[p * 15 + i], a);
        atomicAdd(&bsq[p * 15 + i], b2);
    }
}

// ---------------- k_bn2: BN + ReLU, zF -> hT f32 + hB bf16 ----------
__global__ __launch_bounds__(256) void k_bn2(const float* __restrict__ zF,
                                             const float* __restrict__ bsum,
                                             const float* __restrict__ bsq,
                                             const float* __restrict__ g,
                                             const float* __restrict__ b,
                                             float* __restrict__ hT,
                                             u32* __restrict__ hB) {
    int n = blockIdx.x * 256 + threadIdx.x;
    if (n >= NN) return;
    float buf[80];
    for (int c = 0; c < 75; c++) {
        float mu = bsum[c] * (1.f / NN);
        float var = bsq[c] * (1.f / NN) - mu * mu;
        float sc = g[c] * rsqrtf(var + 1e-5f);
        float v = (zF[(size_t)c * NN + n] - mu) * sc + b[c];
        float r = v > 0.f ? v : 0.f;
        buf[c] = r;
        hT[(size_t)c * NN + n] = r;
    }
#pragma unroll
    for (int c = 75; c < 80; c++) buf[c] = 0.f;
    uint4* bp4 = (uint4*)(hB + (size_t)n * 40);
#pragma unroll
    for (int w = 0; w < 10; w++)
        bp4[w] = make_uint4(pack2(buf[8 * w], buf[8 * w + 1]), pack2(buf[8 * w + 2], buf[8 * w + 3]),
                            pack2(buf[8 * w + 4], buf[8 * w + 5]), pack2(buf[8 * w + 6], buf[8 * w + 7]));
}

// ---------------- MLP head ----------------
__global__ __launch_bounds__(256) void k_mlp1(const float* __restrict__ hT,
                                              const float* __restrict__ alpha,
                                              const int* __restrict__ batch,
                                              const float* __restrict__ w1,
                                              const float* __restrict__ b1,
                                              float* __restrict__ t1) {
    int n = blockIdx.x * 256 + threadIdx.x;
    if (n >= NN) return;
    float acc[50];
#pragma unroll
    for (int j = 0; j < 50; j++) acc[j] = b1[j];
    for (int k = 0; k < 75; k++) {
        float in = hT[(size_t)k * NN + n];
        const float* wr = w1 + k * 50;
#pragma unroll
        for (int j = 0; j < 50; j++) acc[j] = fmaf(in, wr[j], acc[j]);
    }
    float a = alpha[batch[n]];
    const float* wr = w1 + 75 * 50;
#pragma unroll
    for (int j = 0; j < 50; j++) {
        float v = fmaf(a, wr[j], acc[j]);
        t1[(size_t)j * NN + n] = v > 0.f ? v : 0.f;
    }
}

__global__ void k_mlp2(const float* __restrict__ t1, const float* __restrict__ w2,
                       const float* __restrict__ b2, const float* __restrict__ w3,
                       const float* __restrict__ b3, const float* __restrict__ noise,
                       const float* __restrict__ x, float* __restrict__ out) {
    int n = blockIdx.x * 256 + threadIdx.x;
    if (n >= NN) return;
    float tr[50];
#pragma unroll
    for (int k = 0; k < 50; k++) tr[k] = t1[(size_t)k * NN + n];
    float y = b3[0];
#pragma unroll
    for (int k2 = 0; k2 < 25; k2++) {
        float acc = b2[k2];
#pragma unroll
        for (int k = 0; k < 50; k++) acc = fmaf(tr[k], w2[k * 25 + k2], acc);
        acc = acc > 0.f ? acc : 0.f;
        y = fmaf(acc, w3[k2], y);
    }
    float z = y + noise[n];
    float s = 1.f / (1.f + expf(-z));
    out[n] = s;
    out[NN + n] = x[2 * n];
}

extern "C" void kernel_launch(void* const* d_in, const int* in_sizes, int n_in,
                              void* d_out, int out_size, void* d_ws, size_t ws_size,
                              hipStream_t stream) {
    const float* x      = (const float*)d_in[0];
    const float* alpha  = (const float*)d_in[1];
    const int*   ei     = (const int*)d_in[2];
    const int*   batch  = (const int*)d_in[3];
    const float* noise  = (const float*)d_in[4];
    const float* adl    = (const float*)d_in[5];
    const float* pre_w  = (const float*)d_in[6];
    const float* pre_b  = (const float*)d_in[7];
    const float* W_pre  = (const float*)d_in[8];
    const float* b_pre  = (const float*)d_in[9];
    const float* W_post = (const float*)d_in[10];
    const float* b_post = (const float*)d_in[11];
    const float* W_lin  = (const float*)d_in[12];
    const float* b_lin  = (const float*)d_in[13];
    const float* bn_g   = (const float*)d_in[14];
    const float* bn_b   = (const float*)d_in[15];
    const float* mw1    = (const float*)d_in[16];
    const float* mb1    = (const float*)d_in[17];
    const float* mw2    = (const float*)d_in[18];
    const float* mb2    = (const float*)d_in[19];
    const float* mw3    = (const float*)d_in[20];
    const float* mb3    = (const float*)d_in[21];
    (void)in_sizes; (void)n_in; (void)out_size; (void)ws_size;

    char* ws = (char*)d_ws;
    size_t off = 0;
    auto alloc = [&](size_t bytes) -> char* {
        char* p = ws + off;
        off += (bytes + 255) & ~((size_t)255);
        return p;
    };
    float* hT     = (float*)alloc((size_t)75 * NN * 4);        //  9.0 MB (col-major h)
    u32*   hB     = (u32*)alloc((size_t)NN * 40 * 4);          //  4.8 MB
    float* zF     = (float*)alloc((size_t)75 * NN * 4);        //  9.0 MB
    float* tmp0   = (float*)alloc((size_t)75 * NN * 4);        //  9.0 MB
    float* tmp1   = (float*)alloc((size_t)75 * NN * 4);        //  9.0 MB
    u32*   agg32  = (u32*)alloc((size_t)10 * NN * 80 * 4);     // 96.0 MB (family-major)
    u32*   baseb32= (u32*)alloc((size_t)13 * NN * 16 * 4);     // 25.0 MB (padded chunk-major)
    u32*   srcb32 = (u32*)alloc((size_t)13 * NN * 16 * 4);     // 25.0 MB (padded chunk-major)
    float* wqt    = (float*)alloc((size_t)270000 * 4);         //  1.1 MB
    float* Mf     = (float*)alloc((size_t)22500 * 4);          //  90 KB
    float* bladj  = (float*)alloc(300 * 4);
    int*   cnt    = (int*)alloc((size_t)NN * 4);
    int*   offs   = (int*)alloc((size_t)(NN + 1) * 4);
    int*   fill   = (int*)alloc((size_t)NN * 4);
    int*   csr    = (int*)alloc((size_t)EE * 4);
    float* bnsum  = (float*)alloc(4 * 75 * 4);
    float* bnsq   = (float*)alloc(4 * 75 * 4);

    hipMemsetAsync(cnt, 0, (size_t)NN * 4, stream);
    hipMemsetAsync(fill, 0, (size_t)NN * 4, stream);
    hipMemsetAsync(bnsum, 0, 4 * 75 * 4, stream);
    hipMemsetAsync(bnsq, 0, 4 * 75 * 4, stream);

    const int* src = ei;
    const int* dst = ei + EE;
    int eb = (EE + 255) / 256;
    int nb = (NN + 255) / 256;

    k_count<<<eb, 256, 0, stream>>>(dst, cnt);
    k_scan<<<1, 1024, 0, stream>>>(cnt, offs);
    k_scatter<<<eb, 256, 0, stream>>>(src, dst, offs, fill, csr);
    k_pre<<<nb, 256, 0, stream>>>(x, pre_w, pre_b, hT, hB);
    k_wqt<<<(270000 + 255) / 256, 256, 0, stream>>>(W_post, wqt);
    k_badj<<<2, 256, 0, stream>>>(b_lin, b_post, W_lin, bladj);
    k_wm<<<(22500 + 255) / 256, 256, 0, stream>>>(W_post, W_lin, Mf);

    for (int l = 0; l < 4; l++) {
        const float* Wp  = W_pre + (size_t)l * 5 * 150 * 75;
        const float* bp  = b_pre + l * 375;
        const float* wqtl= wqt + (size_t)l * 67500;
        const float* Wl  = W_lin + l * 75 * 75;
        k_base<<<13 * BASE_XS, 256, 0, stream>>>(hB, Wp, bp, baseb32, srcb32);
        k_agg<<<4096, 192, 0, stream>>>(srcb32, csr, offs, baseb32, agg32);
        k_post<<<dim3(nb, 5, 2), 256, 0, stream>>>(offs, agg32, wqtl, adl, tmp0, tmp1);
        k_lin2<<<5 * LIN_XS, 256, 0, stream>>>(tmp0, tmp1, hT, Wl, Mf + l * 5625,
                                               bladj + l * 75, zF,
                                               bnsum + l * 75, bnsq + l * 75);
        k_bn2<<<nb, 256, 0, stream>>>(zF, bnsum + l * 75, bnsq + l * 75,
                                      bn_g + l * 75, bn_b + l * 75, hT, hB);
    }

    float* t1 = tmp0;
    k_mlp1<<<nb, 256, 0, stream>>>(hT, alpha, batch, mw1, mb1, t1);
    k_mlp2<<<nb, 256, 0, stream>>>(t1, mw2, mb2, mw3, mb3, noise, x, (float*)d_out);
}

// Round 16
// 1297.845 us; speedup vs baseline: 1.1684x; 1.1197x over previous
//
#include <hip/hip_runtime.h>
#include <hip/hip_bf16.h>
#include <cstdint>
#include <cstddef>

#define NN 30000
#define EE 150000
#define BASE_XS 64  // k_base x-blocks per chunk-p (>= ceil(15000/256), mult of 8)
#define LIN_XS 120  // k_lin2 x-blocks per p (>= ceil(30000/256)=118, mult of 8)

using u16 = unsigned short;
using u32 = unsigned int;

__device__ __forceinline__ float bl2f(u16 u) { return __uint_as_float(((u32)u) << 16); }
__device__ __forceinline__ u16 f2bl(float f) {
    u32 x = __float_as_uint(f);
    return (u16)((x + 0x7fffu + ((x >> 16) & 1u)) >> 16);
}
__device__ __forceinline__ u32 pack2(float a, float b) {
    return (u32)f2bl(a) | ((u32)f2bl(b) << 16);
}

// ---------------- CSR build ----------------
__global__ void k_count(const int* __restrict__ dst, int* __restrict__ cnt) {
    int e = blockIdx.x * 256 + threadIdx.x;
    if (e < EE) atomicAdd(&cnt[dst[e]], 1);
}

__global__ void k_scan(const int* __restrict__ cnt, int* __restrict__ offs) {
    __shared__ int ss[1024];
    int t = threadIdx.x;
    int base = t * 30;
    int s = 0;
    for (int i = 0; i < 30; i++) { int idx = base + i; if (idx < NN) s += cnt[idx]; }
    ss[t] = s; __syncthreads();
    for (int off = 1; off < 1024; off <<= 1) {
        int v = (t >= off) ? ss[t - off] : 0;
        __syncthreads();
        ss[t] += v;
        __syncthreads();
    }
    int run = (t == 0) ? 0 : ss[t - 1];
    for (int i = 0; i < 30; i++) {
        int idx = base + i;
        if (idx < NN) { offs[idx] = run; run += cnt[idx]; }
    }
    if (t == 1023) offs[NN] = run;
}

__global__ void k_scatter(const int* __restrict__ src, const int* __restrict__ dst,
                          const int* __restrict__ offs, int* __restrict__ fill,
                          int* __restrict__ csr) {
    int e = blockIdx.x * 256 + threadIdx.x;
    if (e < EE) {
        int d = dst[e];
        int p = offs[d] + atomicAdd(&fill[d], 1);
        csr[p] = src[e];
    }
}

// ---------------- k_wqt: transpose agg-part of W_post into c-major layout --------
__global__ void k_wqt(const float* __restrict__ W_post, float* __restrict__ wqt) {
    int idx = blockIdx.x * 256 + threadIdx.x;
    if (idx >= 270000) return;
    int j = idx % 15;
    int grp = (idx / 15) % 3;
    int s4 = (idx / 45) % 4;
    int c = (idx / 180) % 75;
    int lt = idx / 13500;
    wqt[idx] = W_post[(size_t)lt * 975 * 15 + (size_t)(75 + grp * 300 + s4 * 75 + c) * 15 + j];
}

// ---------------- k_badj: bladj[l][c] = bl[c] + sum_k bq[k]*Wl[k][c]  (exact fold) ----
__global__ void k_badj(const float* __restrict__ b_lin, const float* __restrict__ b_post,
                       const float* __restrict__ W_lin, float* __restrict__ bladj) {
    int idx = blockIdx.x * 256 + threadIdx.x;
    if (idx >= 300) return;
    int l = idx / 75, c = idx % 75;
    float a = b_lin[l * 75 + c];
    const float* bq = b_post + l * 75;
    const float* Wl = W_lin + (size_t)l * 75 * 75;
    for (int k = 0; k < 75; k++) a = fmaf(bq[k], Wl[k * 75 + c], a);
    bladj[idx] = a;
}

// ---------------- k_wm: fold x-part through W_lin ----------------
__global__ void k_wm(const float* __restrict__ W_post, const float* __restrict__ W_lin,
                     float* __restrict__ Mf) {
    int idx = blockIdx.x * 256 + threadIdx.x;
    if (idx >= 22500) return;
    int l = idx / 5625;
    int c = (idx / 75) % 75;
    int o = idx % 75;
    const float* Wq = W_post + (size_t)l * 5 * 975 * 15;
    const float* Wl = W_lin + (size_t)l * 75 * 75;
    float a = 0.f;
    for (int t5 = 0; t5 < 5; t5++) {
        const float* wr = Wq + (size_t)t5 * 975 * 15 + (size_t)c * 15;
        const float* lr = Wl + (size_t)(t5 * 15) * 75 + o;
#pragma unroll
        for (int j = 0; j < 15; j++) a = fmaf(wr[j], lr[(size_t)j * 75], a);
    }
    Mf[idx] = a;
}

// ---------------- pre linear: hT[75][NN] f32 (col-major) + hB[n][40] bf16 pairs ------
__global__ void k_pre(const float* __restrict__ x, const float* __restrict__ pw,
                      const float* __restrict__ pb, float* __restrict__ hT,
                      u32* __restrict__ hB) {
    int n = blockIdx.x * 256 + threadIdx.x;
    if (n >= NN) return;
    float x0 = x[2 * n], x1 = x[2 * n + 1];
    float buf[80];
#pragma unroll
    for (int c = 0; c < 80; c++)
        buf[c] = (c < 75) ? fmaf(x0, pw[c], fmaf(x1, pw[75 + c], pb[c])) : 0.f;
#pragma unroll
    for (int c = 0; c < 75; c++)
        hT[(size_t)c * NN + n] = buf[c];
    uint4* bp4 = (uint4*)(hB + (size_t)n * 40);
#pragma unroll
    for (int w = 0; w < 10; w++)
        bp4[w] = make_uint4(pack2(buf[8 * w], buf[8 * w + 1]), pack2(buf[8 * w + 2], buf[8 * w + 3]),
                            pack2(buf[8 * w + 4], buf[8 * w + 5]), pack2(buf[8 * w + 6], buf[8 * w + 7]));
}

// ---- unpack helper: float k (0..7) from uint4 of bf16 pairs ----
__device__ __forceinline__ float upk(const uint4& a, int k) {
    u32 u = (k < 2) ? a.x : (k < 4) ? a.y : (k < 6) ? a.z : a.w;
    return __uint_as_float((k & 1) ? (u & 0xffff0000u) : (u << 16));
}

// ---- shared inner: 2 rows x 30 outputs, uniform weights (wA,wB 15-col slices) ----
__device__ __forceinline__ void gemm30d(const uint4* __restrict__ h0,
                                        const uint4* __restrict__ h1,
                                        const float* __restrict__ wA,
                                        const float* __restrict__ wB,
                                        float acc[2][30]) {
    for (int fq = 0; fq < 9; fq++) {
        uint4 a0 = h0[fq], a1 = h1[fq];
#pragma unroll
        for (int k = 0; k < 8; k++) {
            float i0 = upk(a0, k), i1 = upk(a1, k);
            const float* ra = wA + (fq * 8 + k) * 75;
            const float* rb = wB + (fq * 8 + k) * 75;
#pragma unroll
            for (int j = 0; j < 15; j++) {
                float w = ra[j];
                acc[0][j] = fmaf(i0, w, acc[0][j]); acc[1][j] = fmaf(i1, w, acc[1][j]);
            }
#pragma unroll
            for (int j = 0; j < 15; j++) {
                float w = rb[j];
                acc[0][15 + j] = fmaf(i0, w, acc[0][15 + j]); acc[1][15 + j] = fmaf(i1, w, acc[1][15 + j]);
            }
        }
    }
    uint4 a0 = h0[9], a1 = h1[9];
#pragma unroll
    for (int k = 0; k < 3; k++) {
        float i0 = upk(a0, k), i1 = upk(a1, k);
        const float* ra = wA + (72 + k) * 75;
        const float* rb = wB + (72 + k) * 75;
#pragma unroll
        for (int j = 0; j < 15; j++) {
            float w = ra[j];
            acc[0][j] = fmaf(i0, w, acc[0][j]); acc[1][j] = fmaf(i1, w, acc[1][j]);
        }
#pragma unroll
        for (int j = 0; j < 15; j++) {
            float w = rb[j];
            acc[0][15 + j] = fmaf(i0, w, acc[0][15 + j]); acc[1][15 + j] = fmaf(i1, w, acc[1][15 + j]);
        }
    }
}

// chunk p (0..12) -> weight slice pointers (15-col groups A and B)
__device__ __forceinline__ void chunk_w(int p, const float* Wp, int half_off,
                                        const float** wA, const float** wB, bool* full) {
    int cg = p * 2;
    int tA = cg / 5, cA = (cg % 5) * 15;
    *full = p < 12;
    int cg1 = *full ? cg + 1 : cg;
    int tB = cg1 / 5, cB = (cg1 % 5) * 15;
    *wA = Wp + ((size_t)tA * 150 + half_off) * 75 + cA;
    *wB = Wp + ((size_t)tB * 150 + half_off) * 75 + cB;
}

// ---- pack 30 accs into a 15-u32 (or 8 for tail chunk) row slice ----
__device__ __forceinline__ void pack_row(u32* rp, const float* a, bool full) {
    if (full) {
#pragma unroll
        for (int w = 0; w < 15; w++) rp[w] = pack2(a[2 * w], a[2 * w + 1]);
    } else {
#pragma unroll
        for (int w = 0; w < 7; w++) rp[w] = pack2(a[2 * w], a[2 * w + 1]);
        rp[7] = pack2(a[14], 0.f);
    }
}

// ---------------- k_base: 2 nodes/thread x 13 chunks, BOTH halves ----------------
// 832 blocks all co-resident: 13 p-writers cooperatively assemble each 752 B row
// in L2 (no partial-line RMW) and share the single hB read (FETCH ~4 MB).
// r11/r13/r14/r15 all showed any deviation (bigger grid, LDS staging, chunk-major,
// padded rows) regresses -- this configuration is the validated local optimum.
__global__ __launch_bounds__(256) void k_base(const u32* __restrict__ hB,
                                              const float* __restrict__ Wp,
                                              const float* __restrict__ bp,
                                              u32* __restrict__ baseb32,
                                              u32* __restrict__ srcb32) {
    int b = blockIdx.x;
    int p = b / BASE_XS;
    int xx = b - p * BASE_XS;
    int nq = xx * 256 + threadIdx.x;
    int n = nq * 2;
    if (n >= NN) return;
    const uint4* h0 = (const uint4*)(hB + (size_t)(n + 0) * 40);
    const uint4* h1 = (const uint4*)(hB + (size_t)(n + 1) * 40);
    int o0 = p * 30;
    {   // dst half (with bias)
        const float *wA, *wB; bool full;
        chunk_w(p, Wp, 0, &wA, &wB, &full);
        float acc[2][30];
#pragma unroll
        for (int j = 0; j < 15; j++) {
            float b2 = bp[o0 + j];
            acc[0][j] = b2; acc[1][j] = b2;
        }
#pragma unroll
        for (int j = 0; j < 15; j++) {
            float b2 = full ? bp[o0 + 15 + j] : 0.f;
            acc[0][15 + j] = b2; acc[1][15 + j] = b2;
        }
        gemm30d(h0, h1, wA, wB, acc);
        pack_row(baseb32 + (size_t)n * 188 + p * 15, acc[0], full);
        pack_row(baseb32 + (size_t)(n + 1) * 188 + p * 15, acc[1], full);
    }
    {   // src half (no bias)
        const float *wA, *wB; bool full;
        chunk_w(p, Wp, 75, &wA, &wB, &full);
        float acc[2][30];
#pragma unroll
        for (int j = 0; j < 30; j++) { acc[0][j] = 0.f; acc[1][j] = 0.f; }
        gemm30d(h0, h1, wA, wB, acc);
        pack_row(srcb32 + (size_t)n * 188 + p * 15, acc[0], full);
        pack_row(srcb32 + (size_t)(n + 1) * 188 + p * 15, acc[1], full);
    }
}

// ---------------- k_agg: per-node stats via srcb32 gather; family-major agg32 out ----
// agg32 layout: [fam=t*2+zz][NN][80] u32.
//   zz=0 (c 0..39):  A-word at c,     B-word at 40+c
//   zz=1 (c 40..74): A-word at c-40,  B-word at 36+(c-40) = c-4
__global__ __launch_bounds__(192) void k_agg(const u32* __restrict__ srcb32,
                                             const int* __restrict__ csr,
                                             const int* __restrict__ offs,
                                             const u32* __restrict__ baseb32,
                                             u32* __restrict__ agg32) {
    int q = threadIdx.x;
    if (q >= 188) return;
    int o0 = 2 * q, o1 = 2 * q + 1;
    bool has1 = o1 < 375;
    int t0 = o0 / 75, c0 = o0 % 75;
    int t1 = has1 ? (o1 / 75) : 0, c1 = has1 ? (o1 % 75) : 0;
    int z0 = (c0 >= 40) ? 1 : 0;
    size_t fb0 = (size_t)(t0 * 2 + z0) * NN * 80;
    int a0o = z0 ? (c0 - 40) : c0;
    int b0o = z0 ? (c0 - 4) : (40 + c0);
    int z1 = (c1 >= 40) ? 1 : 0;
    size_t fb1 = (size_t)(t1 * 2 + z1) * NN * 80;
    int a1o = z1 ? (c1 - 40) : c1;
    int b1o = z1 ? (c1 - 4) : (40 + c1);
    for (int v = blockIdx.x; v < NN; v += gridDim.x) {
        int e0 = offs[v], e1 = offs[v + 1];
        float s0 = 0.f, s1 = 0.f, sq0 = 0.f, sq1 = 0.f;
        float mn0 = 3.4e38f, mn1 = 3.4e38f, mx0 = -3.4e38f, mx1 = -3.4e38f;
        for (int e = e0; e < e1; e++) {
            int s = csr[e];
            u32 w = srcb32[(size_t)s * 188 + q];
            float x0 = bl2f((u16)(w & 0xffffu)), x1 = bl2f((u16)(w >> 16));
            s0 += x0; sq0 = fmaf(x0, x0, sq0); mn0 = fminf(mn0, x0); mx0 = fmaxf(mx0, x0);
            s1 += x1; sq1 = fmaf(x1, x1, sq1); mn1 = fminf(mn1, x1); mx1 = fmaxf(mx1, x1);
        }
        int deg = e1 - e0;
        u32 bw = baseb32[(size_t)v * 188 + q];
        float b0 = bl2f((u16)(bw & 0xffffu)), b1 = bl2f((u16)(bw >> 16));
        float mean0, mean1, mnf0, mnf1, mxf0, mxf1, sd0, sd1;
        if (deg > 0) {
            float im = 1.f / (float)deg;
            float mm0 = s0 * im, mm1 = s1 * im;
            float v0 = fmaxf(fmaf(-mm0, mm0, sq0 * im), 0.f);
            float v1 = fmaxf(fmaf(-mm1, mm1, sq1 * im), 0.f);
            sd0 = sqrtf(v0 + 1e-5f); sd1 = sqrtf(v1 + 1e-5f);
            mean0 = b0 + mm0; mean1 = b1 + mm1;
            mnf0 = b0 + mn0;  mnf1 = b1 + mn1;
            mxf0 = b0 + mx0;  mxf1 = b1 + mx1;
        } else {
            float sde = sqrtf(1e-5f);
            mean0 = mean1 = mnf0 = mnf1 = mxf0 = mxf1 = 0.f;
            sd0 = sd1 = sde;
        }
        u32* fp0 = agg32 + fb0 + (size_t)v * 80;
        fp0[a0o] = pack2(mean0, mnf0);
        fp0[b0o] = pack2(mxf0, sd0);
        if (has1) {
            u32* fp1 = agg32 + fb1 + (size_t)v * 80;
            fp1[a1o] = pack2(mean1, mnf1);
            fp1[b1o] = pack2(mxf1, sd1);
        }
    }
}

// ---- one cq (4 c-columns) of the agg GEMM ----
__device__ __forceinline__ void post_cq(int cq, uint4 A, uint4 B, float amp, float inv,
                                        const float* __restrict__ wq, float acc[15]) {
#pragma unroll
    for (int i = 0; i < 4; i++) {
        int c = cq * 4 + i;
        if (c < 75) {
            u32 wA = (i == 0) ? A.x : (i == 1) ? A.y : (i == 2) ? A.z : A.w;
            u32 wB = (i == 0) ? B.x : (i == 1) ? B.y : (i == 2) ? B.z : B.w;
            float vs[4];
            vs[0] = bl2f((u16)(wA & 0xffffu)); vs[1] = bl2f((u16)(wA >> 16));
            vs[2] = bl2f((u16)(wB & 0xffffu)); vs[3] = bl2f((u16)(wB >> 16));
            const float* wc = wq + c * 180;
#pragma unroll
            for (int s4 = 0; s4 < 4; s4++) {
                float a = vs[s4], aa = a * amp, ai = a * inv;
                const float* wb = wc + s4 * 45;
#pragma unroll
                for (int j = 0; j < 15; j++)
                    acc[j] = fmaf(a, wb[j], fmaf(aa, wb[15 + j], fmaf(ai, wb[30 + j], acc[j])));
            }
        }
    }
}

// ---------------- k_post: agg GEMM over family-major agg32 (dense private reads) ----
__global__ __launch_bounds__(256) void k_post(const int* __restrict__ offs,
                                              const u32* __restrict__ agg32,
                                              const float* __restrict__ wqt_l,
                                              const float* __restrict__ adl_p,
                                              float* __restrict__ tmp0,
                                              float* __restrict__ tmp1) {
    int t = blockIdx.y;
    int zz = blockIdx.z;
    int n = blockIdx.x * 256 + threadIdx.x;
    if (n >= NN) return;
    float adl = adl_p[0];
    int deg = offs[n + 1] - offs[n];
    float dc = (float)(deg > 0 ? deg : 1);
    float amp = log1pf(dc) / adl;
    float inv = 1.f / amp;
    const float* wq = wqt_l + (size_t)t * 13500;
    const uint4* ap = (const uint4*)(agg32 + ((size_t)(t * 2 + zz) * NN + n) * 80);
    float acc[15];
#pragma unroll
    for (int j = 0; j < 15; j++) acc[j] = 0.f;
    if (zz == 0) {
        uint4 A[10], B[10];
#pragma unroll
        for (int g = 0; g < 10; g++) { A[g] = ap[g]; B[g] = ap[10 + g]; }
#pragma unroll
        for (int g = 0; g < 10; g++) post_cq(g, A[g], B[g], amp, inv, wq, acc);
#pragma unroll
        for (int j = 0; j < 15; j++) tmp0[(size_t)(t * 15 + j) * NN + n] = acc[j];
    } else {
        uint4 A[9], B[9];
#pragma unroll
        for (int g = 0; g < 9; g++) { A[g] = ap[g]; B[g] = ap[9 + g]; }
#pragma unroll
        for (int g = 0; g < 9; g++) post_cq(10 + g, A[g], B[g], amp, inv, wq, acc);
#pragma unroll
        for (int j = 0; j < 15; j++) tmp1[(size_t)(t * 15 + j) * NN + n] = acc[j];
    }
}

// ---------------- k_lin2: 1D XCD-coherent grid, b = p*LIN_XS + x ----
// LIN_XS % 8 == 0 -> all 5 p-families of node-range x land on XCD x%8 (shared L2
// for the identical tmp/hT columns they read).
__global__ __launch_bounds__(256) void k_lin2(const float* __restrict__ tmp0,
                                              const float* __restrict__ tmp1,
                                              const float* __restrict__ hT,
                                              const float* __restrict__ Wl,
                                              const float* __restrict__ Mf_l,
                                              const float* __restrict__ bladj,
                                              float* __restrict__ zF,
                                              float* __restrict__ bsum,
                                              float* __restrict__ bsq) {
    __shared__ __align__(16) float wl[75][16];
    __shared__ __align__(16) float wm[75][16];
    __shared__ float red1[4][15], red2[4][15];
    int b = blockIdx.x;
    int p = b / LIN_XS;
    int x = b - p * LIN_XS;
    for (int idx = threadIdx.x; idx < 75 * 15; idx += 256) {
        int k = idx / 15, j = idx % 15;
        wl[k][j] = Wl[k * 75 + p * 15 + j];
        wm[k][j] = Mf_l[k * 75 + p * 15 + j];
    }
    __syncthreads();
    int n = x * 256 + threadIdx.x;
    bool valid = n < NN;
    int nc = valid ? n : NN - 1;
    float acc[15];
#pragma unroll
    for (int j = 0; j < 15; j++) acc[j] = bladj[p * 15 + j];
    for (int k = 0; k < 75; k++) {
        float a = tmp0[(size_t)k * NN + nc] + tmp1[(size_t)k * NN + nc];
        float h = hT[(size_t)k * NN + nc];
        float4 w0 = *(const float4*)&wl[k][0];
        float4 w1 = *(const float4*)&wl[k][4];
        float4 w2 = *(const float4*)&wl[k][8];
        float4 w3 = *(const float4*)&wl[k][12];
        float4 m0 = *(const float4*)&wm[k][0];
        float4 m1 = *(const float4*)&wm[k][4];
        float4 m2 = *(const float4*)&wm[k][8];
        float4 m3 = *(const float4*)&wm[k][12];
        acc[0]  = fmaf(h, m0.x, fmaf(a, w0.x, acc[0]));
        acc[1]  = fmaf(h, m0.y, fmaf(a, w0.y, acc[1]));
        acc[2]  = fmaf(h, m0.z, fmaf(a, w0.z, acc[2]));
        acc[3]  = fmaf(h, m0.w, fmaf(a, w0.w, acc[3]));
        acc[4]  = fmaf(h, m1.x, fmaf(a, w1.x, acc[4]));
        acc[5]  = fmaf(h, m1.y, fmaf(a, w1.y, acc[5]));
        acc[6]  = fmaf(h, m1.z, fmaf(a, w1.z, acc[6]));
        acc[7]  = fmaf(h, m1.w, fmaf(a, w1.w, acc[7]));
        acc[8]  = fmaf(h, m2.x, fmaf(a, w2.x, acc[8]));
        acc[9]  = fmaf(h, m2.y, fmaf(a, w2.y, acc[9]));
        acc[10] = fmaf(h, m2.z, fmaf(a, w2.z, acc[10]));
        acc[11] = fmaf(h, m2.w, fmaf(a, w2.w, acc[11]));
        acc[12] = fmaf(h, m3.x, fmaf(a, w3.x, acc[12]));
        acc[13] = fmaf(h, m3.y, fmaf(a, w3.y, acc[13]));
        acc[14] = fmaf(h, m3.z, fmaf(a, w3.z, acc[14]));
    }
    if (valid) {
#pragma unroll
        for (int j = 0; j < 15; j++)
            zF[(size_t)(p * 15 + j) * NN + n] = acc[j];
    }
    float s[15], ss[15];
#pragma unroll
    for (int i = 0; i < 15; i++) {
        float a = valid ? acc[i] : 0.f;
        s[i] = a; ss[i] = a * a;
    }
    for (int d = 32; d > 0; d >>= 1) {
#pragma unroll
        for (int i = 0; i < 15; i++) {
            s[i] += __shfl_down(s[i], d);
            ss[i] += __shfl_down(ss[i], d);
        }
    }
    int wave = threadIdx.x >> 6, lane = threadIdx.x & 63;
    if (lane == 0) {
#pragma unroll
        for (int i = 0; i < 15; i++) { red1[wave][i] = s[i]; red2[wave][i] = ss[i]; }
    }
    __syncthreads();
    if (threadIdx.x < 15) {
        int i = threadIdx.x;
        float a = red1[0][i] + red1[1][i] + red1[2][i] + red1[3][i];
        float b2 = red2[0][i] + red2[1][i] + red2[2][i] + red2[3][i];
        atomicAdd(&bsum[p * 15 + i], a);
        atomicAdd(&bsq[p * 15 + i], b2);
    }
}

// ---------------- k_bn2: BN + ReLU, zF -> hT f32 + hB bf16 ----------
__global__ __launch_bounds__(256) void k_bn2(const float* __restrict__ zF,
                                             const float* __restrict__ bsum,
                                             const float* __restrict__ bsq,
                                             const float* __restrict__ g,
                                             const float* __restrict__ b,
                                             float* __restrict__ hT,
                                             u32* __restrict__ hB) {
    int n = blockIdx.x * 256 + threadIdx.x;
    if (n >= NN) return;
    float buf[80];
    for (int c = 0; c < 75; c++) {
        float mu = bsum[c] * (1.f / NN);
        float var = bsq[c] * (1.f / NN) - mu * mu;
        float sc = g[c] * rsqrtf(var + 1e-5f);
        float v = (zF[(size_t)c * NN + n] - mu) * sc + b[c];
        float r = v > 0.f ? v : 0.f;
        buf[c] = r;
        hT[(size_t)c * NN + n] = r;
    }
#pragma unroll
    for (int c = 75; c < 80; c++) buf[c] = 0.f;
    uint4* bp4 = (uint4*)(hB + (size_t)n * 40);
#pragma unroll
    for (int w = 0; w < 10; w++)
        bp4[w] = make_uint4(pack2(buf[8 * w], buf[8 * w + 1]), pack2(buf[8 * w + 2], buf[8 * w + 3]),
                            pack2(buf[8 * w + 4], buf[8 * w + 5]), pack2(buf[8 * w + 6], buf[8 * w + 7]));
}

// ---------------- MLP head ----------------
__global__ __launch_bounds__(256) void k_mlp1(const float* __restrict__ hT,
                                              const float* __restrict__ alpha,
                                              const int* __restrict__ batch,
                                              const float* __restrict__ w1,
                                              const float* __restrict__ b1,
                                              float* __restrict__ t1) {
    int n = blockIdx.x * 256 + threadIdx.x;
    if (n >= NN) return;
    float acc[50];
#pragma unroll
    for (int j = 0; j < 50; j++) acc[j] = b1[j];
    for (int k = 0; k < 75; k++) {
        float in = hT[(size_t)k * NN + n];
        const float* wr = w1 + k * 50;
#pragma unroll
        for (int j = 0; j < 50; j++) acc[j] = fmaf(in, wr[j], acc[j]);
    }
    float a = alpha[batch[n]];
    const float* wr = w1 + 75 * 50;
#pragma unroll
    for (int j = 0; j < 50; j++) {
        float v = fmaf(a, wr[j], acc[j]);
        t1[(size_t)j * NN + n] = v > 0.f ? v : 0.f;
    }
}

__global__ void k_mlp2(const float* __restrict__ t1, const float* __restrict__ w2,
                       const float* __restrict__ b2, const float* __restrict__ w3,
                       const float* __restrict__ b3, const float* __restrict__ noise,
                       const float* __restrict__ x, float* __restrict__ out) {
    int n = blockIdx.x * 256 + threadIdx.x;
    if (n >= NN) return;
    float tr[50];
#pragma unroll
    for (int k = 0; k < 50; k++) tr[k] = t1[(size_t)k * NN + n];
    float y = b3[0];
#pragma unroll
    for (int k2 = 0; k2 < 25; k2++) {
        float acc = b2[k2];
#pragma unroll
        for (int k = 0; k < 50; k++) acc = fmaf(tr[k], w2[k * 25 + k2], acc);
        acc = acc > 0.f ? acc : 0.f;
        y = fmaf(acc, w3[k2], y);
    }
    float z = y + noise[n];
    float s = 1.f / (1.f + expf(-z));
    out[n] = s;
    out[NN + n] = x[2 * n];
}

extern "C" void kernel_launch(void* const* d_in, const int* in_sizes, int n_in,
                              void* d_out, int out_size, void* d_ws, size_t ws_size,
                              hipStream_t stream) {
    const float* x      = (const float*)d_in[0];
    const float* alpha  = (const float*)d_in[1];
    const int*   ei     = (const int*)d_in[2];
    const int*   batch  = (const int*)d_in[3];
    const float* noise  = (const float*)d_in[4];
    const float* adl    = (const float*)d_in[5];
    const float* pre_w  = (const float*)d_in[6];
    const float* pre_b  = (const float*)d_in[7];
    const float* W_pre  = (const float*)d_in[8];
    const float* b_pre  = (const float*)d_in[9];
    const float* W_post = (const float*)d_in[10];
    const float* b_post = (const float*)d_in[11];
    const float* W_lin  = (const float*)d_in[12];
    const float* b_lin  = (const float*)d_in[13];
    const float* bn_g   = (const float*)d_in[14];
    const float* bn_b   = (const float*)d_in[15];
    const float* mw1    = (const float*)d_in[16];
    const float* mb1    = (const float*)d_in[17];
    const float* mw2    = (const float*)d_in[18];
    const float* mb2    = (const float*)d_in[19];
    const float* mw3    = (const float*)d_in[20];
    const float* mb3    = (const float*)d_in[21];
    (void)in_sizes; (void)n_in; (void)out_size; (void)ws_size;

    char* ws = (char*)d_ws;
    size_t off = 0;
    auto alloc = [&](size_t bytes) -> char* {
        char* p = ws + off;
        off += (bytes + 255) & ~((size_t)255);
        return p;
    };
    float* hT     = (float*)alloc((size_t)75 * NN * 4);        //  9.0 MB (col-major h)
    u32*   hB     = (u32*)alloc((size_t)NN * 40 * 4);          //  4.8 MB
    float* zF     = (float*)alloc((size_t)75 * NN * 4);        //  9.0 MB
    float* tmp0   = (float*)alloc((size_t)75 * NN * 4);        //  9.0 MB
    float* tmp1   = (float*)alloc((size_t)75 * NN * 4);        //  9.0 MB
    u32*   agg32  = (u32*)alloc((size_t)10 * NN * 80 * 4);     // 96.0 MB (family-major)
    u32*   baseb32= (u32*)alloc((size_t)NN * 188 * 4);         // 22.6 MB
    u32*   srcb32 = (u32*)alloc((size_t)NN * 188 * 4);         // 22.6 MB (per-node src msgs)
    float* wqt    = (float*)alloc((size_t)270000 * 4);         //  1.1 MB
    float* Mf     = (float*)alloc((size_t)22500 * 4);          //  90 KB
    float* bladj  = (float*)alloc(300 * 4);
    int*   cnt    = (int*)alloc((size_t)NN * 4);
    int*   offs   = (int*)alloc((size_t)(NN + 1) * 4);
    int*   fill   = (int*)alloc((size_t)NN * 4);
    int*   csr    = (int*)alloc((size_t)EE * 4);
    float* bnsum  = (float*)alloc(4 * 75 * 4);
    float* bnsq   = (float*)alloc(4 * 75 * 4);

    hipMemsetAsync(cnt, 0, (size_t)NN * 4, stream);
    hipMemsetAsync(fill, 0, (size_t)NN * 4, stream);
    hipMemsetAsync(bnsum, 0, 4 * 75 * 4, stream);
    hipMemsetAsync(bnsq, 0, 4 * 75 * 4, stream);

    const int* src = ei;
    const int* dst = ei + EE;
    int eb = (EE + 255) / 256;
    int nb = (NN + 255) / 256;

    k_count<<<eb, 256, 0, stream>>>(dst, cnt);
    k_scan<<<1, 1024, 0, stream>>>(cnt, offs);
    k_scatter<<<eb, 256, 0, stream>>>(src, dst, offs, fill, csr);
    k_pre<<<nb, 256, 0, stream>>>(x, pre_w, pre_b, hT, hB);
    k_wqt<<<(270000 + 255) / 256, 256, 0, stream>>>(W_post, wqt);
    k_badj<<<2, 256, 0, stream>>>(b_lin, b_post, W_lin, bladj);
    k_wm<<<(22500 + 255) / 256, 256, 0, stream>>>(W_post, W_lin, Mf);

    for (int l = 0; l < 4; l++) {
        const float* Wp  = W_pre + (size_t)l * 5 * 150 * 75;
        const float* bp  = b_pre + l * 375;
        const float* wqtl= wqt + (size_t)l * 67500;
        const float* Wl  = W_lin + l * 75 * 75;
        k_base<<<13 * BASE_XS, 256, 0, stream>>>(hB, Wp, bp, baseb32, srcb32);
        k_agg<<<4096, 192, 0, stream>>>(srcb32, csr, offs, baseb32, agg32);
        k_post<<<dim3(nb, 5, 2), 256, 0, stream>>>(offs, agg32, wqtl, adl, tmp0, tmp1);
        k_lin2<<<5 * LIN_XS, 256, 0, stream>>>(tmp0, tmp1, hT, Wl, Mf + l * 5625,
                                               bladj + l * 75, zF,
                                               bnsum + l * 75, bnsq + l * 75);
        k_bn2<<<nb, 256, 0, stream>>>(zF, bnsum + l * 75, bnsq + l * 75,
                                      bn_g + l * 75, bn_b + l * 75, hT, hB);
    }

    float* t1 = tmp0;
    k_mlp1<<<nb, 256, 0, stream>>>(hT, alpha, batch, mw1, mb1, t1);
    k_mlp2<<<nb, 256, 0, stream>>>(t1, mw2, mb2, mw3, mb3, noise, x, (float*)d_out);
}